// Round 3
// baseline (375.857 us; speedup 1.0000x reference)
//
#include <hip/hip_runtime.h>

// B=8, T=20, C=1, H=512, W=512
#define FRAMES 160
#define HH 512
#define WW 512
#define STRIPS 16
#define NBLK (STRIPS * FRAMES)   // 2560
#define NTOT 41943040

// SSIM on raw [0,1) values (scale-invariant: C1,C2 divided by 255^2),
// numerator/denominator premultiplied by NP^2 (NP=49):
//   A1 = 2ab + 2401*C1            B1 = a^2+b^2 + 2401*C1
//   A2 = (49/24)(49*sxy - ab) + 2401*C2
//   B2 = (49/48)(49(sxx+syy) - (a^2+b^2)) + 2401*C2
__device__ __forceinline__ float ssim_fast(float a, float b, float sxx,
                                           float syy, float sxy) {
  const float K1 = 0.2401f;        // 2401 * 1e-4
  const float K2 = 2.1609f;        // 2401 * 9e-4
  const float cA = 49.0f / 24.0f;
  const float cB = 49.0f / 48.0f;
  float ab = a * b;
  float s2 = fmaf(a, a, b * b);
  float A1 = fmaf(2.0f, ab, K1);
  float B1 = s2 + K1;
  float A2 = fmaf(cA, fmaf(49.0f, sxy, -ab), K2);
  float B2 = fmaf(cB, fmaf(49.0f, sxx + syy, -s2), K2);
  return (A1 * A2) * __builtin_amdgcn_rcpf(B1 * B2);
}

// prefix within the thread's 4 columns, store (P0,P1) / (P2,P3) to LDS
#define HSTORE(S, P, A)                          \
  P.x = S.x; P.y = P.x + S.y;                    \
  P.z = P.y + S.z; P.w = P.z + S.w;              \
  lds[grp][A][0][q] = make_float2(P.x, P.y);     \
  lds[grp][A][1][q] = make_float2(P.z, P.w);

// 7-wide windows at cols 4q..4q+3 from own prefixes + neighbor prefixes
#define HWIN(P, W, A) {                          \
  float2 h1 = lds[grp][A][1][q + 1];             \
  float2 l2 = lds[grp][A][0][q + 2];             \
  W.x = P.w + h1.x;                              \
  W.y = (P.w - P.x) + h1.y;                      \
  W.z = (P.w - P.y) + (h1.y + l2.x);             \
  W.w = (P.w - P.z) + (h1.y + l2.y); }

#define LREC(xv, yv) {                                         \
  float4 d_ = make_float4(xv.x - yv.x, xv.y - yv.y,            \
                          xv.z - yv.z, xv.w - yv.w);           \
  sabs += fabsf(d_.x) + fabsf(d_.y) + fabsf(d_.z) + fabsf(d_.w); \
  ssq += d_.x * d_.x + d_.y * d_.y;                            \
  ssq += d_.z * d_.z + d_.w * d_.w; }

#define VADD(xv, yv)                                    \
  Sx += xv; Sy += yv;                                   \
  Sxx += xv * xv; Syy += yv * yv; Sxy += xv * yv;

#define VSUB(xv, yv)                                    \
  Sx -= xv; Sy -= yv;                                   \
  Sxx -= xv * xv; Syy -= yv * yv; Sxy -= xv * yv;

// grid (STRIPS, FRAMES), block 256 = two 128-thread groups.
// Group 0 (waves 0-1): even relative output rows; group 1: odd rows.
// Thread q in a group owns cols 4q..4q+3. Strip s covers output rows
// [32s, 32s+n_out), n_out = 32 (s<15) or 26 (s=15); owns input rows
// [32s, 32s+32) for L_rec (grp0 counts rel<=30 on first touch, grp1 rel==31).
__global__ __launch_bounds__(256) void fused_kernel(
    const float* __restrict__ gsrc, const float* __restrict__ tsrc,
    float* __restrict__ ws) {
  const int strip = blockIdx.x;
  const int frame = blockIdx.y;
  const int row0 = strip * 32;
  const int n_iter = (strip == STRIPS - 1) ? 13 : 16;  // output-row pairs
  const int tid = threadIdx.x;
  const int grp = tid >> 7;
  const int q = tid & 127;

  const float* gp = gsrc + ((size_t)frame * HH + row0 + grp) * WW + q * 4;
  const float* tp = tsrc + ((size_t)frame * HH + row0 + grp) * WW + q * 4;

  __shared__ float2 lds[2][5][2][132];  // [group][array][lo/hi][q(+pad)]

  float4 Sx = make_float4(0.f, 0.f, 0.f, 0.f);
  float4 Sy = Sx, Sxx = Sx, Syy = Sx, Sxy = Sx;
  float sabs = 0.f, ssq = 0.f, ssum = 0.f;

  // init window: rel rows grp..grp+6 (grp0's rows 0..6 are all owned)
  for (int i = 0; i < 7; ++i) {
    float4 xv = *(const float4*)(gp + i * WW);
    float4 yv = *(const float4*)(tp + i * WW);
    VADD(xv, yv)
    if (grp == 0) { LREC(xv, yv) }
  }

  for (int it = 0; it < n_iter; ++it) {
    float4 Px, Py, Pxx, Pyy, Pxy;
    HSTORE(Sx, Px, 0) HSTORE(Sy, Py, 1) HSTORE(Sxx, Pxx, 2)
    HSTORE(Syy, Pyy, 3) HSTORE(Sxy, Pxy, 4)
    __syncthreads();
    float4 Wx, Wy, Wxx, Wyy, Wxy;
    HWIN(Px, Wx, 0) HWIN(Py, Wy, 1) HWIN(Pxx, Wxx, 2)
    HWIN(Pyy, Wyy, 3) HWIN(Pxy, Wxy, 4)
    float v0 = ssim_fast(Wx.x, Wy.x, Wxx.x, Wyy.x, Wxy.x);
    float v1 = ssim_fast(Wx.y, Wy.y, Wxx.y, Wyy.y, Wxy.y);
    float v2 = ssim_fast(Wx.z, Wy.z, Wxx.z, Wyy.z, Wxy.z);
    float v3 = ssim_fast(Wx.w, Wy.w, Wxx.w, Wyy.w, Wxy.w);
    // valid output cols: 4q+j <= 505 (506 outputs); select-then-add is
    // NaN-safe against garbage in the LDS pad region.
    ssum += (q <= 126) ? v0 : 0.f;
    ssum += (q <= 126) ? v1 : 0.f;
    ssum += (q <= 125) ? v2 : 0.f;
    ssum += (q <= 125) ? v3 : 0.f;
    __syncthreads();  // protect LDS against next iteration's writes

    if (it + 1 < n_iter) {
      // slide window by 2: add rel rows (2it+7,2it+8)+grp, retire
      // (2it,2it+1)+grp. Retire rows re-read from global: exact same
      // values as when added -> exact cancellation, no register ring.
      const float* pn = gp + (size_t)(2 * it + 7) * WW;
      const float* qn = tp + (size_t)(2 * it + 7) * WW;
      const float* po = gp + (size_t)(2 * it) * WW;
      const float* qo = tp + (size_t)(2 * it) * WW;
      {
        float4 nx = *(const float4*)pn;
        float4 ny = *(const float4*)qn;
        float4 ox = *(const float4*)po;
        float4 oy = *(const float4*)qo;
        VADD(nx, ny)
        VSUB(ox, oy)
        if ((grp == 0) && (2 * it + 7 <= 30)) { LREC(nx, ny) }
      }
      {
        float4 nx = *(const float4*)(pn + WW);
        float4 ny = *(const float4*)(qn + WW);
        float4 ox = *(const float4*)(po + WW);
        float4 oy = *(const float4*)(qo + WW);
        VADD(nx, ny)
        VSUB(ox, oy)
        bool cnt = (grp == 0) ? (2 * it + 8 <= 30) : (2 * it + 9 == 31);
        if (cnt) { LREC(nx, ny) }
      }
    }
  }

  // block reduce sabs / ssq / ssum
  #pragma unroll
  for (int off = 32; off > 0; off >>= 1) {
    sabs += __shfl_down(sabs, off, 64);
    ssq += __shfl_down(ssq, off, 64);
    ssum += __shfl_down(ssum, off, 64);
  }
  float* scr = (float*)&lds[0][0][0][0];
  const int lane = tid & 63, wv = tid >> 6;
  if (lane == 0) { scr[wv] = sabs; scr[4 + wv] = ssq; scr[8 + wv] = ssum; }
  __syncthreads();
  if (tid == 0) {
    const int bid = blockIdx.y * STRIPS + blockIdx.x;
    ws[bid] = scr[0] + scr[1] + scr[2] + scr[3];
    ws[NBLK + bid] = scr[4] + scr[5] + scr[6] + scr[7];
    ws[2 * NBLK + bid] = scr[8] + scr[9] + scr[10] + scr[11];
  }
}

__global__ __launch_bounds__(256) void finalize_kernel(
    const float* __restrict__ ws, const float* __restrict__ genD,
    float* __restrict__ out) {
  const int tid = threadIdx.x;
  float a = 0.f, b = 0.f, c = 0.f;
  for (int i = tid; i < NBLK; i += 256) {
    a += ws[i];
    b += ws[NBLK + i];
    c += ws[2 * NBLK + i];
  }
  #pragma unroll
  for (int off = 32; off > 0; off >>= 1) {
    a += __shfl_down(a, off, 64);
    b += __shfl_down(b, off, 64);
    c += __shfl_down(c, off, 64);
  }
  __shared__ float la[4], lb[4], lc[4];
  const int lane = tid & 63, wv = tid >> 6;
  if (lane == 0) { la[wv] = a; lb[wv] = b; lc[wv] = c; }
  __syncthreads();
  if (tid == 0) {
    a = la[0] + la[1] + la[2] + la[3];
    b = lb[0] + lb[1] + lb[2] + lb[3];
    c = lc[0] + lc[1] + lc[2] + lc[3];
    const float invN = 1.0f / (float)NTOT;
    float L_rec = a * invN + b * invN;
    float L_ssim = c / (160.0f * 506.0f * 506.0f);
    float d = 0.f;
    #pragma unroll
    for (int i = 0; i < 8; ++i) d += genD[i];
    float L_adv = -d / 8.0f;
    float L_total = L_rec + 0.01f * (1.0f - L_ssim) + 0.0001f * L_adv;
    out[0] = L_total;
    out[1] = L_rec;
    out[2] = L_ssim;
    out[3] = L_adv;
  }
}

extern "C" void kernel_launch(void* const* d_in, const int* in_sizes, int n_in,
                              void* d_out, int out_size, void* d_ws,
                              size_t ws_size, hipStream_t stream) {
  const float* gen_img = (const float*)d_in[0];
  const float* target = (const float*)d_in[1];
  const float* gen_D = (const float*)d_in[2];
  float* out = (float*)d_out;
  float* ws = (float*)d_ws;

  dim3 grid(STRIPS, FRAMES);
  fused_kernel<<<grid, 256, 0, stream>>>(gen_img, target, ws);
  finalize_kernel<<<1, 256, 0, stream>>>(ws, gen_D, out);
}

// Round 4
// 355.475 us; speedup vs baseline: 1.0573x; 1.0573x over previous
//
#include <hip/hip_runtime.h>

// B=8, T=20, C=1, H=512, W=512
#define FRAMES 160
#define HH 512
#define WW 512
#define STRIPS 16
#define NBLK (STRIPS * FRAMES)   // 2560
#define NTOT 41943040

// LDS-only barrier (composable_kernel's block_sync_lds): waits lgkmcnt(0)
// but NOT vmcnt -> prefetched global loads stay in flight across barriers.
// 0xC07F = vmcnt 63 (no wait), expcnt 7 (no wait), lgkmcnt 0 (wait all).
__device__ __forceinline__ void sync_lds() {
  __builtin_amdgcn_s_waitcnt(0xC07F);
  __builtin_amdgcn_s_barrier();
}

// SSIM on raw [0,1) values (scale-invariant: C1,C2 divided by 255^2),
// numerator/denominator premultiplied by NP^2 (NP=49).
__device__ __forceinline__ float ssim_fast(float a, float b, float sxx,
                                           float syy, float sxy) {
  const float K1 = 0.2401f;        // 2401 * 1e-4
  const float K2 = 2.1609f;        // 2401 * 9e-4
  const float cA = 49.0f / 24.0f;
  const float cB = 49.0f / 48.0f;
  float ab = a * b;
  float s2 = fmaf(a, a, b * b);
  float A1 = fmaf(2.0f, ab, K1);
  float B1 = s2 + K1;
  float A2 = fmaf(cA, fmaf(49.0f, sxy, -ab), K2);
  float B2 = fmaf(cB, fmaf(49.0f, sxx + syy, -s2), K2);
  return (A1 * A2) * __builtin_amdgcn_rcpf(B1 * B2);
}

// prefix within the thread's 4 columns, store (P0,P1) / (P2,P3) to LDS
#define HSTORE(S, P, A)                          \
  P.x = S.x; P.y = P.x + S.y;                    \
  P.z = P.y + S.z; P.w = P.z + S.w;              \
  lds[grp][A][0][q] = make_float2(P.x, P.y);     \
  lds[grp][A][1][q] = make_float2(P.z, P.w);

// 7-wide windows at cols 4q..4q+3 from own prefixes + neighbor prefixes
#define HWIN(P, W, A) {                          \
  float2 h1 = lds[grp][A][1][q + 1];             \
  float2 l2 = lds[grp][A][0][q + 2];             \
  W.x = P.w + h1.x;                              \
  W.y = (P.w - P.x) + h1.y;                      \
  W.z = (P.w - P.y) + (h1.y + l2.x);             \
  W.w = (P.w - P.z) + (h1.y + l2.y); }

#define LREC(xv, yv) {                                         \
  float4 d_ = make_float4(xv.x - yv.x, xv.y - yv.y,            \
                          xv.z - yv.z, xv.w - yv.w);           \
  sabs += fabsf(d_.x) + fabsf(d_.y) + fabsf(d_.z) + fabsf(d_.w); \
  ssq += d_.x * d_.x + d_.y * d_.y;                            \
  ssq += d_.z * d_.z + d_.w * d_.w; }

#define VADD(xv, yv)                                    \
  Sx += xv; Sy += yv;                                   \
  Sxx += xv * xv; Syy += yv * yv; Sxy += xv * yv;

#define VSUB(xv, yv)                                    \
  Sx -= xv; Sy -= yv;                                   \
  Sxx -= xv * xv; Syy -= yv * yv; Sxy -= xv * yv;

// grid (STRIPS, FRAMES), block 256 = two 128-thread groups.
// Group 0 (waves 0-1): even relative output rows; group 1: odd rows.
// Thread q in a group owns cols 4q..4q+3. Strip s covers output rows
// [32s, 32s+n_out), n_out = 32 (s<15) or 26 (s=15); owns input rows
// [32s, 32s+32) for L_rec (grp0 counts rel<=30 on first touch, grp1 rel==31).
__global__ __launch_bounds__(256, 4) void fused_kernel(
    const float* __restrict__ gsrc, const float* __restrict__ tsrc,
    float* __restrict__ ws) {
  const int strip = blockIdx.x;
  const int frame = blockIdx.y;
  const int row0 = strip * 32;
  const int n_iter = (strip == STRIPS - 1) ? 13 : 16;  // output-row pairs
  const int tid = threadIdx.x;
  const int grp = tid >> 7;
  const int q = tid & 127;

  const float* gp = gsrc + ((size_t)frame * HH + row0 + grp) * WW + q * 4;
  const float* tp = tsrc + ((size_t)frame * HH + row0 + grp) * WW + q * 4;

  __shared__ float2 lds[2][5][2][132];  // [group][array][lo/hi][q(+pad)]

  float4 Sx = make_float4(0.f, 0.f, 0.f, 0.f);
  float4 Sy = Sx, Sxx = Sx, Syy = Sx, Sxy = Sx;
  float sabs = 0.f, ssq = 0.f, ssum = 0.f;

  // init window: rel rows grp..grp+6 (grp0's rows 0..6 are all owned)
  for (int i = 0; i < 7; ++i) {
    float4 xv = *(const float4*)(gp + i * WW);
    float4 yv = *(const float4*)(tp + i * WW);
    VADD(xv, yv)
    if (grp == 0) { LREC(xv, yv) }
  }

  for (int it = 0; it < n_iter; ++it) {
    const bool slide = (it + 1 < n_iter);
    // ---- prefetch the slide rows NOW; consume after the barriers ----
    float4 nx0, ny0, nx1, ny1, ox0, oy0, ox1, oy1;
    if (slide) {
      const float* pn = gp + (size_t)(2 * it + 7) * WW;
      const float* qn = tp + (size_t)(2 * it + 7) * WW;
      const float* po = gp + (size_t)(2 * it) * WW;
      const float* qo = tp + (size_t)(2 * it) * WW;
      nx0 = *(const float4*)pn;
      ny0 = *(const float4*)qn;
      nx1 = *(const float4*)(pn + WW);
      ny1 = *(const float4*)(qn + WW);
      ox0 = *(const float4*)po;
      oy0 = *(const float4*)qo;
      ox1 = *(const float4*)(po + WW);
      oy1 = *(const float4*)(qo + WW);
    }

    float4 Px, Py, Pxx, Pyy, Pxy;
    HSTORE(Sx, Px, 0) HSTORE(Sy, Py, 1) HSTORE(Sxx, Pxx, 2)
    HSTORE(Syy, Pyy, 3) HSTORE(Sxy, Pxy, 4)
    sync_lds();  // lgkm-only: prefetched vm loads stay in flight
    float4 Wx, Wy, Wxx, Wyy, Wxy;
    HWIN(Px, Wx, 0) HWIN(Py, Wy, 1) HWIN(Pxx, Wxx, 2)
    HWIN(Pyy, Wyy, 3) HWIN(Pxy, Wxy, 4)
    float v0 = ssim_fast(Wx.x, Wy.x, Wxx.x, Wyy.x, Wxy.x);
    float v1 = ssim_fast(Wx.y, Wy.y, Wxx.y, Wyy.y, Wxy.y);
    float v2 = ssim_fast(Wx.z, Wy.z, Wxx.z, Wyy.z, Wxy.z);
    float v3 = ssim_fast(Wx.w, Wy.w, Wxx.w, Wyy.w, Wxy.w);
    // valid output cols: 4q+j <= 505 (506 outputs); select-then-add is
    // NaN-safe against garbage in the LDS pad region.
    ssum += (q <= 126) ? v0 : 0.f;
    ssum += (q <= 126) ? v1 : 0.f;
    ssum += (q <= 125) ? v2 : 0.f;
    ssum += (q <= 125) ? v3 : 0.f;
    sync_lds();  // protect LDS for next iteration's writes

    if (slide) {
      // consume prefetched rows: add rel (2it+7,2it+8)+grp, retire
      // (2it,2it+1)+grp. Retired rows re-read from global: exact same
      // values as when added -> exact cancellation.
      VADD(nx0, ny0)
      VSUB(ox0, oy0)
      if ((grp == 0) && (2 * it + 7 <= 30)) { LREC(nx0, ny0) }
      VADD(nx1, ny1)
      VSUB(ox1, oy1)
      bool cnt = (grp == 0) ? (2 * it + 8 <= 30) : (2 * it + 9 == 31);
      if (cnt) { LREC(nx1, ny1) }
    }
  }

  // block reduce sabs / ssq / ssum
  #pragma unroll
  for (int off = 32; off > 0; off >>= 1) {
    sabs += __shfl_down(sabs, off, 64);
    ssq += __shfl_down(ssq, off, 64);
    ssum += __shfl_down(ssum, off, 64);
  }
  __syncthreads();  // full barrier before reusing lds as scratch
  float* scr = (float*)&lds[0][0][0][0];
  const int lane = tid & 63, wv = tid >> 6;
  if (lane == 0) { scr[wv] = sabs; scr[4 + wv] = ssq; scr[8 + wv] = ssum; }
  __syncthreads();
  if (tid == 0) {
    const int bid = blockIdx.y * STRIPS + blockIdx.x;
    ws[bid] = scr[0] + scr[1] + scr[2] + scr[3];
    ws[NBLK + bid] = scr[4] + scr[5] + scr[6] + scr[7];
    ws[2 * NBLK + bid] = scr[8] + scr[9] + scr[10] + scr[11];
  }
}

__global__ __launch_bounds__(256) void finalize_kernel(
    const float* __restrict__ ws, const float* __restrict__ genD,
    float* __restrict__ out) {
  const int tid = threadIdx.x;
  float a = 0.f, b = 0.f, c = 0.f;
  for (int i = tid; i < NBLK; i += 256) {
    a += ws[i];
    b += ws[NBLK + i];
    c += ws[2 * NBLK + i];
  }
  #pragma unroll
  for (int off = 32; off > 0; off >>= 1) {
    a += __shfl_down(a, off, 64);
    b += __shfl_down(b, off, 64);
    c += __shfl_down(c, off, 64);
  }
  __shared__ float la[4], lb[4], lc[4];
  const int lane = tid & 63, wv = tid >> 6;
  if (lane == 0) { la[wv] = a; lb[wv] = b; lc[wv] = c; }
  __syncthreads();
  if (tid == 0) {
    a = la[0] + la[1] + la[2] + la[3];
    b = lb[0] + lb[1] + lb[2] + lb[3];
    c = lc[0] + lc[1] + lc[2] + lc[3];
    const float invN = 1.0f / (float)NTOT;
    float L_rec = a * invN + b * invN;
    float L_ssim = c / (160.0f * 506.0f * 506.0f);
    float d = 0.f;
    #pragma unroll
    for (int i = 0; i < 8; ++i) d += genD[i];
    float L_adv = -d / 8.0f;
    float L_total = L_rec + 0.01f * (1.0f - L_ssim) + 0.0001f * L_adv;
    out[0] = L_total;
    out[1] = L_rec;
    out[2] = L_ssim;
    out[3] = L_adv;
  }
}

extern "C" void kernel_launch(void* const* d_in, const int* in_sizes, int n_in,
                              void* d_out, int out_size, void* d_ws,
                              size_t ws_size, hipStream_t stream) {
  const float* gen_img = (const float*)d_in[0];
  const float* target = (const float*)d_in[1];
  const float* gen_D = (const float*)d_in[2];
  float* out = (float*)d_out;
  float* ws = (float*)d_ws;

  dim3 grid(STRIPS, FRAMES);
  fused_kernel<<<grid, 256, 0, stream>>>(gen_img, target, ws);
  finalize_kernel<<<1, 256, 0, stream>>>(ws, gen_D, out);
}